// Round 3
// baseline (356.560 us; speedup 1.0000x reference)
//
#include <hip/hip_runtime.h>
#include <stdint.h>

// Problem constants (fixed shapes from reference)
#define M_DIM 4096   // 2 * 2048 rows of x
#define K_DIM 4096   // in_features
#define N_DIM 4096   // out_features

typedef float f32x4  __attribute__((ext_vector_type(4)));
typedef int   i32x4  __attribute__((ext_vector_type(4)));
typedef int   i32x16 __attribute__((ext_vector_type(16)));

// ---------------------------------------------------------------------------
// Fused quant kernel: blocks 0..4095 quantize x rows; 4096..8191 dequant+quant
// W rows. Bodies identical to R2's quant_x / quant_w (only fused to drop one
// launch and let the two BW-bound halves overlap).
// ---------------------------------------------------------------------------
__global__ __launch_bounds__(256) void quant_xw(const float* __restrict__ x,
                                                const int* __restrict__ packed,
                                                const float* __restrict__ d,
                                                const float* __restrict__ dmin,
                                                const int* __restrict__ scales,
                                                const int* __restrict__ mins,
                                                int8_t* __restrict__ xq,
                                                float* __restrict__ sx,
                                                int8_t* __restrict__ wq,
                                                float* __restrict__ sw) {
    __shared__ float sa[128], sb[128], red[4];
    if (blockIdx.x < 4096) {
        // ---- x fp32 -> i8, per-row scale ----
        const int row  = blockIdx.x;
        const int base = threadIdx.x * 16;
        const float* xr = x + (size_t)row * K_DIM + base;
        float4 v[4];
#pragma unroll
        for (int c = 0; c < 4; ++c) v[c] = ((const float4*)xr)[c];
        float am = 0.f;
#pragma unroll
        for (int c = 0; c < 4; ++c) {
            am = fmaxf(am, fabsf(v[c].x)); am = fmaxf(am, fabsf(v[c].y));
            am = fmaxf(am, fabsf(v[c].z)); am = fmaxf(am, fabsf(v[c].w));
        }
#pragma unroll
        for (int off = 32; off; off >>= 1) am = fmaxf(am, __shfl_xor(am, off, 64));
        if ((threadIdx.x & 63) == 0) red[threadIdx.x >> 6] = am;
        __syncthreads();
        float amax = fmaxf(fmaxf(red[0], red[1]), fmaxf(red[2], red[3]));
        amax = fmaxf(amax, 1e-20f);
        const float inv = 127.0f / amax;
        int ow[4];
#pragma unroll
        for (int c = 0; c < 4; ++c) {
            int q0 = __float2int_rn(v[c].x * inv);
            int q1 = __float2int_rn(v[c].y * inv);
            int q2 = __float2int_rn(v[c].z * inv);
            int q3 = __float2int_rn(v[c].w * inv);
            ow[c] = (q0 & 255) | ((q1 & 255) << 8) | ((q2 & 255) << 16) | ((q3 & 255) << 24);
        }
        ((int4*)(xq + (size_t)row * K_DIM + base))[0] = make_int4(ow[0], ow[1], ow[2], ow[3]);
        if (threadIdx.x == 0) sx[row] = amax / 127.0f;
    } else {
        // ---- Q4_K dequant -> i8 W, per-row scale ----
        const int n = blockIdx.x - 4096;
        const int t = threadIdx.x;
        float m = 0.f;
        if (t < 128) {
            int sub  = n * 128 + t;
            int sidx = n * 16 + (t >> 3);
            float dd = d[sidx], dm = dmin[sidx];
            float a = dd * (float)scales[sub] * (1.0f / 945.0f);
            float b = dd * (float)mins[sub] * (1.0f / 63.0f) + dm;
            sa[t] = a; sb[t] = b;
            m = 15.0f * a + b;
        }
#pragma unroll
        for (int off = 32; off; off >>= 1) m = fmaxf(m, __shfl_xor(m, off, 64));
        if ((t & 63) == 0) red[t >> 6] = m;
        __syncthreads();
        float rowmax = fmaxf(fmaxf(red[0], red[1]), fmaxf(red[2], red[3]));
        rowmax = fmaxf(rowmax, 1e-20f);
        const float inv = 127.0f / rowmax;

        const int sub = t >> 1;                    // 16 weights = half a subblock
        const float a = sa[sub] * inv;
        const float b = sb[sub] * inv;
        const int4* p4 = (const int4*)(packed + (size_t)n * (K_DIM / 2) + t * 8);
        int4 pv0 = p4[0], pv1 = p4[1];
        int bytes[8] = {pv0.x, pv0.y, pv0.z, pv0.w, pv1.x, pv1.y, pv1.z, pv1.w};
        int ow[4];
#pragma unroll
        for (int c = 0; c < 4; ++c) {
            int b0 = bytes[2 * c], b1 = bytes[2 * c + 1];
            int q0 = __float2int_rn((float)(b0 & 15) * a + b);
            int q1 = __float2int_rn((float)((b0 >> 4) & 15) * a + b);
            int q2 = __float2int_rn((float)(b1 & 15) * a + b);
            int q3 = __float2int_rn((float)((b1 >> 4) & 15) * a + b);
            ow[c] = (q0 & 255) | ((q1 & 255) << 8) | ((q2 & 255) << 16) | ((q3 & 255) << 24);
        }
        ((int4*)(wq + (size_t)n * K_DIM + t * 16))[0] = make_int4(ow[0], ow[1], ow[2], ow[3]);
        if (t == 0) sw[n] = rowmax / 127.0f;
    }
}

// ---------------------------------------------------------------------------
// GEMM: C[M,N](fp32) = sx[m]*sw[n] * (Aq . Bq^T), i8 MFMA 32x32x32.
// 256x256 tile, BK=128 B, 512 thr / 8 waves (2M x 4N), 128 KiB LDS.
//
// R3 changes (theory: LDS pipe ~4600 cy/iter fully serialized vs MFMA 5224):
//  - mfma_i32_32x32x32_i8 (4404 vs 3944 TOPS; half the MFMA instr count).
//  - dedicated bF0/bF1 register sets: LDS reads at minimum 24/K-tile/wave.
//  - 4 phases/iter (32 MFMA per barrier), counted vmcnt W=4/2/4/2.
//
// Per iter j: tiles u=2j (buf0), v=2j+1 (buf1).
//  P1: Q00,Q01(u)  weave aF<-A1(u)                 stage B1(v),A1(v)   W=4
//  P2: Q11,Q10(u)  weave aF<-A0(v),bF0,bF1<-B*(v)  stage A0,B0(u+2)    W=2
//  P3: Q00,Q01(v)  weave aF<-A1(v)                 stage B1,A1(u+2)    W=4
//  P4: Q11,Q10(v)  weave aF<-A0(u+2),bF*<-B*(u+2)  stage A0,B0(v+2)    W=2
// FIFO desk-check: W retires exactly through each phase's weave sources;
// every stage overwrites a region whose last reader is >=2 barriers back.
//
// LDS layout (per buf/half, 128 rows x 128 B): chunk c of row r at slot
// c ^ (r&7) (involution on stage-source and read; rule #21).
// ---------------------------------------------------------------------------
#define BK 128   // bytes of K per K-tile (4 MFMA k-steps of 32)

__device__ __forceinline__ void async_copy16(void* lds, const void* g) {
    __builtin_amdgcn_global_load_lds(
        (const __attribute__((address_space(1))) void*)g,
        (__attribute__((address_space(3))) void*)lds, 16, 0, 0);
}

#define BARRIER() asm volatile("s_barrier" ::: "memory")
#define WAITV(n)  asm volatile("s_waitcnt vmcnt(" #n ")" ::: "memory")
#define mfma32(a, b, c) __builtin_amdgcn_mfma_i32_32x32x32_i8(a, b, c, 0, 0, 0)

__global__ __launch_bounds__(512, 2) void gemm_i8(const int8_t* __restrict__ A,
                                                  const int8_t* __restrict__ B,
                                                  const float* __restrict__ sx,
                                                  const float* __restrict__ sw,
                                                  float* __restrict__ C) {
    __shared__ int8_t sA[2][2][128 * 128];
    __shared__ int8_t sB[2][2][128 * 128];

    const int tid  = threadIdx.x;
    const int wave = tid >> 6;
    const int lane = tid & 63;
    const int wm  = wave >> 2;      // 0..1
    const int wn  = wave & 3;       // 0..3
    const int l31 = lane & 31;
    const int hi  = lane >> 5;

    // XCD-aware bijective swizzle: 256 blocks = 8 XCDs x 32 contiguous tiles
    const int bid = blockIdx.x;
    const int lid = (bid & 7) * 32 + (bid >> 3);
    const int m0 = (lid & 15) * 256;
    const int n0 = (lid >> 4) * 256;

    i32x16 acc[2][2][2] = {};       // [a][b][mb]  (8 x 16 = 128 acc regs)
    i32x4  aF[2][4];                // [mb][ks]    current A-half frags
    i32x4  bF0[4], bF1[4];          // [ks]        B0 / B1 frags (no re-reads)

    // ---- staging map (unchanged bytes): load l in {0,1}: chunk p=l*512+tid,
    // row = p>>3, slot = p&7, logical chunk c = slot ^ (row&7).
    const int rowS = tid >> 3;
    const int cS   = (tid & 7) ^ (rowS & 7);
    const size_t rs64 = (size_t)64 * K_DIM;
    const int8_t* gAh[2];
    const int8_t* gBh[2];
    gAh[0] = A + (size_t)(m0 + rowS) * K_DIM + cS * 16;
    gAh[1] = gAh[0] + (size_t)128 * K_DIM;
    gBh[0] = B + (size_t)(n0 + rowS) * K_DIM + cS * 16;
    gBh[1] = gBh[0] + (size_t)128 * K_DIM;
    const int ldsW = wave * 1024;   // wave-uniform dest base

#define STAGE_A(buf, half, koff)                                          \
    do {                                                                  \
        async_copy16(&sA[buf][half][ldsW],        gAh[half] + (koff));    \
        async_copy16(&sA[buf][half][ldsW + 8192], gAh[half] + rs64 + (koff)); \
    } while (0)
#define STAGE_B(buf, half, koff)                                          \
    do {                                                                  \
        async_copy16(&sB[buf][half][ldsW],        gBh[half] + (koff));    \
        async_copy16(&sB[buf][half][ldsW + 8192], gBh[half] + rs64 + (koff)); \
    } while (0)

    // ---- fragment LDS offsets (32x32x32 layout: row = l&31, k = hi*16+j) --
    int aOff[2][4], bOff[4];
#pragma unroll
    for (int mb = 0; mb < 2; ++mb) {
        const int r = wm * 64 + mb * 32 + l31;
#pragma unroll
        for (int ks = 0; ks < 4; ++ks)
            aOff[mb][ks] = r * 128 + (((ks * 2 + hi) ^ (r & 7)) * 16);
    }
    {
        const int r = wn * 32 + l31;
#pragma unroll
        for (int ks = 0; ks < 4; ++ks)
            bOff[ks] = r * 128 + (((ks * 2 + hi) ^ (r & 7)) * 16);
    }

#define RD_A(buf, half, mb, ks) (*(const i32x4*)&sA[buf][half][aOff[mb][ks]])
#define RD_B(buf, half, ks)     (*(const i32x4*)&sB[buf][half][bOff[ks]])

// First half of a tile: Q00,Q01 with aF=A0(tile); weave aF<-A1 from buf tb.
#define PH_A(tb)                                                          \
    do {                                                                  \
        __builtin_amdgcn_s_setprio(1);                                    \
        _Pragma("unroll") for (int ks = 0; ks < 4; ++ks) {                \
            acc[0][0][0] = mfma32(aF[0][ks], bF0[ks], acc[0][0][0]);      \
            acc[0][0][1] = mfma32(aF[1][ks], bF0[ks], acc[0][0][1]);      \
        }                                                                 \
        _Pragma("unroll") for (int ks = 0; ks < 4; ++ks) {                \
            acc[0][1][0] = mfma32(aF[0][ks], bF1[ks], acc[0][1][0]);      \
            aF[0][ks] = RD_A(tb, 1, 0, ks);                               \
            acc[0][1][1] = mfma32(aF[1][ks], bF1[ks], acc[0][1][1]);      \
            aF[1][ks] = RD_A(tb, 1, 1, ks);                               \
        }                                                                 \
        __builtin_amdgcn_s_setprio(0);                                    \
    } while (0)

// Second half: Q11,Q10 with aF=A1(tile); weave next tile's frags from nbuf.
#define PH_B(nbuf)                                                        \
    do {                                                                  \
        __builtin_amdgcn_s_setprio(1);                                    \
        _Pragma("unroll") for (int ks = 0; ks < 4; ++ks) {                \
            acc[1][1][0] = mfma32(aF[0][ks], bF1[ks], acc[1][1][0]);      \
            acc[1][1][1] = mfma32(aF[1][ks], bF1[ks], acc[1][1][1]);      \
            bF1[ks] = RD_B(nbuf, 1, ks);                                  \
        }                                                                 \
        _Pragma("unroll") for (int ks = 0; ks < 4; ++ks) {                \
            acc[1][0][0] = mfma32(aF[0][ks], bF0[ks], acc[1][0][0]);      \
            aF[0][ks] = RD_A(nbuf, 0, 0, ks);                             \
            acc[1][0][1] = mfma32(aF[1][ks], bF0[ks], acc[1][0][1]);      \
            aF[1][ks] = RD_A(nbuf, 0, 1, ks);                             \
            bF0[ks] = RD_B(nbuf, 0, ks);                                  \
        }                                                                 \
        __builtin_amdgcn_s_setprio(0);                                    \
    } while (0)

// Final second half: no weaves.
#define PH_B_END()                                                        \
    do {                                                                  \
        __builtin_amdgcn_s_setprio(1);                                    \
        _Pragma("unroll") for (int ks = 0; ks < 4; ++ks) {                \
            acc[1][1][0] = mfma32(aF[0][ks], bF1[ks], acc[1][1][0]);      \
            acc[1][1][1] = mfma32(aF[1][ks], bF1[ks], acc[1][1][1]);      \
        }                                                                 \
        _Pragma("unroll") for (int ks = 0; ks < 4; ++ks) {                \
            acc[1][0][0] = mfma32(aF[0][ks], bF0[ks], acc[1][0][0]);      \
            acc[1][0][1] = mfma32(aF[1][ks], bF0[ks], acc[1][0][1]);      \
        }                                                                 \
        __builtin_amdgcn_s_setprio(0);                                    \
    } while (0)

    // ---- prologue: tile0 full + tile1 A0,B0; preload tile0 frags ----
    STAGE_A(0, 0, 0);
    STAGE_B(0, 0, 0);
    STAGE_B(0, 1, 0);
    STAGE_A(0, 1, 0);
    STAGE_A(1, 0, BK);
    STAGE_B(1, 0, BK);
    WAITV(4);                 // tile0's 8 loads retired; tile1's 4 in flight
    BARRIER();
#pragma unroll
    for (int mb = 0; mb < 2; ++mb)
#pragma unroll
        for (int ks = 0; ks < 4; ++ks) aF[mb][ks] = RD_A(0, 0, mb, ks);
#pragma unroll
    for (int ks = 0; ks < 4; ++ks) { bF0[ks] = RD_B(0, 0, ks); bF1[ks] = RD_B(0, 1, ks); }

    int koB1 = BK, koU2 = 2 * BK, koV2 = 3 * BK;
#pragma unroll 1
    for (int j = 0; j < 15; ++j) {
        // P1: Q00,Q01(u); stage B1(v),A1(v)
        WAITV(4);
        STAGE_B(1, 1, koB1); STAGE_A(1, 1, koB1);
        PH_A(0);
        BARRIER();
        // P2: Q11,Q10(u); weaves <- buf1 (tile v); stage A0,B0(u+2)
        WAITV(2);
        STAGE_A(0, 0, koU2); STAGE_B(0, 0, koU2);
        PH_B(1);
        BARRIER();
        // P3: Q00,Q01(v); stage B1,A1(u+2)
        WAITV(4);
        STAGE_B(0, 1, koU2); STAGE_A(0, 1, koU2);
        PH_A(1);
        BARRIER();
        // P4: Q11,Q10(v); weaves <- buf0 (tile u+2); stage A0,B0(v+2)
        WAITV(2);
        STAGE_A(1, 0, koV2); STAGE_B(1, 0, koV2);
        PH_B(0);
        BARRIER();
        koB1 += 2 * BK; koU2 += 2 * BK; koV2 += 2 * BK;
    }

    // ---- epilogue iter: u=30, v=31; stage only B1,A1(31); drain ----
    WAITV(4);
    STAGE_B(1, 1, koB1); STAGE_A(1, 1, koB1);
    PH_A(0);
    BARRIER();
    WAITV(2);                 // A0,B0,B1(31) retired
    PH_B(1);
    BARRIER();
    WAITV(0);                 // A1(31) retired
    PH_A(1);
    BARRIER();
    PH_B_END();

    // ---- C write: 32x32 C/D layout col = lane&31, row = (reg&3)+8*(reg>>2)+4*hi
#pragma unroll
    for (int a = 0; a < 2; ++a)
#pragma unroll
    for (int mb = 0; mb < 2; ++mb) {
        const int row0 = m0 + a * 128 + wm * 64 + mb * 32 + hi * 4;
#pragma unroll
        for (int b = 0; b < 2; ++b) {
            const int col = n0 + b * 128 + wn * 32 + l31;
            const float swc = sw[col];
#pragma unroll
            for (int g = 0; g < 4; ++g) {
                const int rbase = row0 + 8 * g;
                const float4 s4 = *(const float4*)&sx[rbase];
                float* cp = C + (size_t)rbase * N_DIM + col;
                cp[0 * N_DIM] = (float)acc[a][b][mb][4 * g + 0] * s4.x * swc;
                cp[1 * N_DIM] = (float)acc[a][b][mb][4 * g + 1] * s4.y * swc;
                cp[2 * N_DIM] = (float)acc[a][b][mb][4 * g + 2] * s4.z * swc;
                cp[3 * N_DIM] = (float)acc[a][b][mb][4 * g + 3] * s4.w * swc;
            }
        }
    }
#undef STAGE_A
#undef STAGE_B
#undef RD_A
#undef RD_B
#undef PH_A
#undef PH_B
#undef PH_B_END
}

// ---------------------------------------------------------------------------
// Launch: ws usage = 16.7 MB xq + 16.7 MB wq + 32 KB scales.
// ---------------------------------------------------------------------------
extern "C" void kernel_launch(void* const* d_in, const int* in_sizes, int n_in,
                              void* d_out, int out_size, void* d_ws, size_t ws_size,
                              hipStream_t stream) {
    const float* x      = (const float*)d_in[0];
    const int*   packed = (const int*)d_in[1];
    const float* d      = (const float*)d_in[2];
    const float* dmin   = (const float*)d_in[3];
    const int*   scales = (const int*)d_in[4];
    const int*   mins   = (const int*)d_in[5];
    float* out = (float*)d_out;

    int8_t* xq = (int8_t*)d_ws;                               // 16.7 MB
    int8_t* wq = xq + (size_t)M_DIM * K_DIM;                  // 16.7 MB
    float*  sx = (float*)(wq + (size_t)N_DIM * K_DIM);        // 16 KB
    float*  sw = sx + M_DIM;                                  // 16 KB

    quant_xw<<<8192, 256, 0, stream>>>(x, packed, d, dmin, scales, mins,
                                       xq, sx, wq, sw);
    gemm_i8<<<256, 512, 0, stream>>>(xq, wq, sx, sw, out);
}

// Round 4
// 215.396 us; speedup vs baseline: 1.6554x; 1.6554x over previous
//
#include <hip/hip_runtime.h>
#include <stdint.h>

// Problem constants (fixed shapes from reference)
#define M_DIM 4096   // 2 * 2048 rows of x
#define K_DIM 4096   // in_features
#define N_DIM 4096   // out_features

typedef float f32x4 __attribute__((ext_vector_type(4)));
typedef int   i32x4 __attribute__((ext_vector_type(4)));

// ---------------------------------------------------------------------------
// Fused quant kernel: blocks 0..4095 quantize x rows; 4096..8191 dequant+quant
// W rows. (unchanged from R3 — fusion was neutral-to-positive)
// ---------------------------------------------------------------------------
__global__ __launch_bounds__(256) void quant_xw(const float* __restrict__ x,
                                                const int* __restrict__ packed,
                                                const float* __restrict__ d,
                                                const float* __restrict__ dmin,
                                                const int* __restrict__ scales,
                                                const int* __restrict__ mins,
                                                int8_t* __restrict__ xq,
                                                float* __restrict__ sx,
                                                int8_t* __restrict__ wq,
                                                float* __restrict__ sw) {
    __shared__ float sa[128], sb[128], red[4];
    if (blockIdx.x < 4096) {
        const int row  = blockIdx.x;
        const int base = threadIdx.x * 16;
        const float* xr = x + (size_t)row * K_DIM + base;
        float4 v[4];
#pragma unroll
        for (int c = 0; c < 4; ++c) v[c] = ((const float4*)xr)[c];
        float am = 0.f;
#pragma unroll
        for (int c = 0; c < 4; ++c) {
            am = fmaxf(am, fabsf(v[c].x)); am = fmaxf(am, fabsf(v[c].y));
            am = fmaxf(am, fabsf(v[c].z)); am = fmaxf(am, fabsf(v[c].w));
        }
#pragma unroll
        for (int off = 32; off; off >>= 1) am = fmaxf(am, __shfl_xor(am, off, 64));
        if ((threadIdx.x & 63) == 0) red[threadIdx.x >> 6] = am;
        __syncthreads();
        float amax = fmaxf(fmaxf(red[0], red[1]), fmaxf(red[2], red[3]));
        amax = fmaxf(amax, 1e-20f);
        const float inv = 127.0f / amax;
        int ow[4];
#pragma unroll
        for (int c = 0; c < 4; ++c) {
            int q0 = __float2int_rn(v[c].x * inv);
            int q1 = __float2int_rn(v[c].y * inv);
            int q2 = __float2int_rn(v[c].z * inv);
            int q3 = __float2int_rn(v[c].w * inv);
            ow[c] = (q0 & 255) | ((q1 & 255) << 8) | ((q2 & 255) << 16) | ((q3 & 255) << 24);
        }
        ((int4*)(xq + (size_t)row * K_DIM + base))[0] = make_int4(ow[0], ow[1], ow[2], ow[3]);
        if (threadIdx.x == 0) sx[row] = amax / 127.0f;
    } else {
        const int n = blockIdx.x - 4096;
        const int t = threadIdx.x;
        float m = 0.f;
        if (t < 128) {
            int sub  = n * 128 + t;
            int sidx = n * 16 + (t >> 3);
            float dd = d[sidx], dm = dmin[sidx];
            float a = dd * (float)scales[sub] * (1.0f / 945.0f);
            float b = dd * (float)mins[sub] * (1.0f / 63.0f) + dm;
            sa[t] = a; sb[t] = b;
            m = 15.0f * a + b;
        }
#pragma unroll
        for (int off = 32; off; off >>= 1) m = fmaxf(m, __shfl_xor(m, off, 64));
        if ((t & 63) == 0) red[t >> 6] = m;
        __syncthreads();
        float rowmax = fmaxf(fmaxf(red[0], red[1]), fmaxf(red[2], red[3]));
        rowmax = fmaxf(rowmax, 1e-20f);
        const float inv = 127.0f / rowmax;

        const int sub = t >> 1;
        const float a = sa[sub] * inv;
        const float b = sb[sub] * inv;
        const int4* p4 = (const int4*)(packed + (size_t)n * (K_DIM / 2) + t * 8);
        int4 pv0 = p4[0], pv1 = p4[1];
        int bytes[8] = {pv0.x, pv0.y, pv0.z, pv0.w, pv1.x, pv1.y, pv1.z, pv1.w};
        int ow[4];
#pragma unroll
        for (int c = 0; c < 4; ++c) {
            int b0 = bytes[2 * c], b1 = bytes[2 * c + 1];
            int q0 = __float2int_rn((float)(b0 & 15) * a + b);
            int q1 = __float2int_rn((float)((b0 >> 4) & 15) * a + b);
            int q2 = __float2int_rn((float)(b1 & 15) * a + b);
            int q3 = __float2int_rn((float)((b1 >> 4) & 15) * a + b);
            ow[c] = (q0 & 255) | ((q1 & 255) << 8) | ((q2 & 255) << 16) | ((q3 & 255) << 24);
        }
        ((int4*)(wq + (size_t)n * K_DIM + t * 16))[0] = make_int4(ow[0], ow[1], ow[2], ow[3]);
        if (t == 0) sw[n] = rowmax / 127.0f;
    }
}

// ---------------------------------------------------------------------------
// GEMM: C[M,N](fp32) = sx[m]*sw[n] * (Aq . Bq^T), i8 MFMA 16x16x64 (reverted
// from R3's failed 32x32: +540MB scratch-class HBM traffic, 6.3M bank confl).
//
// R4 = R2 skeleton with two provable cuts:
//  (a) wave grid 4M x 2N (wave tile 64x128): each wave's A region (64 rows)
//      and B region (one 128-col half) are CONTIGUOUS -> LDS reads hit the
//      24 KB/wave/tile minimum (R2's 128x64 tile provably needs >=1 re-read:
//      4 operand-pair adjacencies, only 3 path edges -> 28 KB).
//  (b) 2 barriers/tile instead of 4: B ring grp0..3 weave + A weave at tile
//      end. 32 MFMA per barrier window, counted WAITV(2) only.
//
// Tile t (buf p=t&1): bF ping-pong bFa/bFb; aF holds A(t) all tile.
//   W1: [stage B0(t+1),B1(t+1),A0(t+2)] grp0 MFMA+weave grp1 ->bFb;
//       [stage A1(t+2)] grp1 MFMA+weave grp2 ->bFa;   WAITV(2); BARRIER
//   W2: grp2 MFMA+weave grp3 ->bFb;
//       grp3 MFMA+weave A(t+1)->aF, grp0(t+1)->bFa;   WAITV(2); BARRIER
// FIFO desk-check (steady state, 4 stage-events/tile of {6,2,0,0} loads):
//   W1(t) queue=[A1(t+1):2, P1(t):6, P2(t):2] -> WAITV(2) retires A1(t+1)+
//   P1(t) = exactly what window-2 reads [grp3(t) old; A(t+1); grp0(t+1)] need.
//   W2 is a no-op (2 in flight, never drains). Every stage overwrites a
//   region whose last cross-wave read is >=1 barrier back (checked all 4).
// LDS layout unchanged: chunk c of row r at slot c^(r&7) (involution both
// sides, rule #21); fragment slots identical to R2 (0 measured conflicts).
// ---------------------------------------------------------------------------
#define BK 128   // bytes of K per K-tile (2 MFMA k-steps of 64)

__device__ __forceinline__ void async_copy16(void* lds, const void* g) {
    __builtin_amdgcn_global_load_lds(
        (const __attribute__((address_space(1))) void*)g,
        (__attribute__((address_space(3))) void*)lds, 16, 0, 0);
}

#define BARRIER() asm volatile("s_barrier" ::: "memory")
#define WAITV(n)  asm volatile("s_waitcnt vmcnt(" #n ")" ::: "memory")
#define LGKM0()   asm volatile("s_waitcnt lgkmcnt(0)" ::: "memory")
#define mfma64(a, b, c) __builtin_amdgcn_mfma_i32_16x16x64_i8(a, b, c, 0, 0, 0)

__global__ __launch_bounds__(512, 2) void gemm_i8(const int8_t* __restrict__ A,
                                                  const int8_t* __restrict__ B,
                                                  const float* __restrict__ sx,
                                                  const float* __restrict__ sw,
                                                  float* __restrict__ C) {
    // [buf][half][128 rows * 128 B] — 128 KiB total
    __shared__ int8_t sA[2][2][128 * 128];
    __shared__ int8_t sB[2][2][128 * 128];

    const int tid  = threadIdx.x;
    const int wave = tid >> 6;
    const int lane = tid & 63;
    const int wm = wave >> 1;       // 0..3  (M split)
    const int wn = wave & 1;        // 0..1  (N split = B half)
    const int r4 = lane & 15;
    const int q  = lane >> 4;
    const int ah = wm >> 1;         // wave's A half region

    // XCD-aware bijective swizzle: 256 blocks = 8 XCDs x 32 contiguous tiles
    const int bid = blockIdx.x;
    const int lid = (bid & 7) * 32 + (bid >> 3);
    const int m0 = (lid & 15) * 256;
    const int n0 = (lid >> 4) * 256;

    i32x4 acc[4][8] = {};           // [m][n] -> 128 acc regs
    i32x4 aF[2][4];                 // [ks][m]  A(t), held all tile
    i32x4 bFa[2][2], bFb[2][2];     // [ks][nn] ping-pong B groups

    // ---- staging map: load l in {0,1}: chunk p = l*512 + tid ----
    // row = p>>3, slot = p&7, logical chunk c = slot ^ (row&7).
    const int rowS = tid >> 3;
    const int cS   = (tid & 7) ^ (rowS & 7);
    const size_t rs64 = (size_t)64 * K_DIM;
    const int8_t* gAh[2];
    const int8_t* gBh[2];
    gAh[0] = A + (size_t)(m0 + rowS) * K_DIM + cS * 16;
    gAh[1] = gAh[0] + (size_t)128 * K_DIM;
    gBh[0] = B + (size_t)(n0 + rowS) * K_DIM + cS * 16;
    gBh[1] = gBh[0] + (size_t)128 * K_DIM;
    const int ldsW = wave * 1024;   // wave-uniform dest base

#define STAGE_A(buf, half, koff)                                          \
    do {                                                                  \
        async_copy16(&sA[buf][half][ldsW],        gAh[half] + (koff));    \
        async_copy16(&sA[buf][half][ldsW + 8192], gAh[half] + rs64 + (koff)); \
    } while (0)
#define STAGE_B(buf, half, koff)                                          \
    do {                                                                  \
        async_copy16(&sB[buf][half][ldsW],        gBh[half] + (koff));    \
        async_copy16(&sB[buf][half][ldsW + 8192], gBh[half] + rs64 + (koff)); \
    } while (0)

    // ---- fragment LDS base offsets (frag index adds n*2048 / m*2048) ----
    int aOffB[2], bOffB[2];
#pragma unroll
    for (int ks = 0; ks < 2; ++ks) {
        const int sl = (((ks * 4 + q) ^ (r4 & 7)) * 16);
        aOffB[ks] = ((wm & 1) * 64 + r4) * 128 + sl;   // row&7 == r4&7
        bOffB[ks] = r4 * 128 + sl;                     // n*16 keeps row&7
    }

#define RD_A(buf, ks, m) (*(const i32x4*)&sA[buf][ah][aOffB[ks] + (m) * 2048])
#define RD_B(buf, ks, n) (*(const i32x4*)&sB[buf][wn][bOffB[ks] + (n) * 2048])

// 16 MFMA for B-group g (operands BC), weaving group ng into BN from buf rb.
#define MMA_BW(g, BC, BN, rb, ng)                                         \
    do {                                                                  \
        __builtin_amdgcn_s_setprio(1);                                    \
        _Pragma("unroll") for (int m = 0; m < 4; ++m) {                   \
            _Pragma("unroll") for (int nn = 0; nn < 2; ++nn) {            \
                acc[m][2*(g)+nn] = mfma64(aF[0][m], BC[0][nn], acc[m][2*(g)+nn]); \
                acc[m][2*(g)+nn] = mfma64(aF[1][m], BC[1][nn], acc[m][2*(g)+nn]); \
            }                                                             \
            BN[m & 1][m >> 1] = RD_B(rb, m & 1, 2*(ng) + (m >> 1));       \
        }                                                                 \
        __builtin_amdgcn_s_setprio(0);                                    \
    } while (0)

// grp3 + weave next tile's A (after each m's last use) and grp0 from buf nb.
#define MMA_P4(BC, BN, nb)                                                \
    do {                                                                  \
        __builtin_amdgcn_s_setprio(1);                                    \
        _Pragma("unroll") for (int m = 0; m < 4; ++m) {                   \
            _Pragma("unroll") for (int nn = 0; nn < 2; ++nn) {            \
                acc[m][6+nn] = mfma64(aF[0][m], BC[0][nn], acc[m][6+nn]); \
                acc[m][6+nn] = mfma64(aF[1][m], BC[1][nn], acc[m][6+nn]); \
            }                                                             \
            aF[0][m] = RD_A(nb, 0, m);                                    \
            aF[1][m] = RD_A(nb, 1, m);                                    \
            BN[m & 1][m >> 1] = RD_B(nb, m & 1, (m >> 1));                \
        }                                                                 \
        __builtin_amdgcn_s_setprio(0);                                    \
    } while (0)

// grp3 with no weaves (final tile).
#define MMA_END(BC)                                                       \
    do {                                                                  \
        __builtin_amdgcn_s_setprio(1);                                    \
        _Pragma("unroll") for (int m = 0; m < 4; ++m)                     \
        _Pragma("unroll") for (int nn = 0; nn < 2; ++nn) {                \
            acc[m][6+nn] = mfma64(aF[0][m], BC[0][nn], acc[m][6+nn]);     \
            acc[m][6+nn] = mfma64(aF[1][m], BC[1][nn], acc[m][6+nn]);     \
        }                                                                 \
        __builtin_amdgcn_s_setprio(0);                                    \
    } while (0)

// One full tile: 64 MFMA, 2 barriers, stages {B(t+1), A(t+2)}.
#define TILE(p, koA, koB)                                                 \
    do {                                                                  \
        STAGE_B((p)^1, 0, koB); STAGE_B((p)^1, 1, koB); STAGE_A(p, 0, koA); \
        MMA_BW(0, bFa, bFb, p, 1);                                        \
        STAGE_A(p, 1, koA);                                               \
        MMA_BW(1, bFb, bFa, p, 2);                                        \
        WAITV(2); BARRIER();                                              \
        MMA_BW(2, bFa, bFb, p, 3);                                        \
        MMA_P4(bFb, bFa, (p)^1);                                          \
        WAITV(2); BARRIER();                                              \
    } while (0)

    // ---- prologue: stage tile0; retire; preload frags; then A(1) ----
    STAGE_A(0, 0, 0); STAGE_A(0, 1, 0); STAGE_B(0, 0, 0); STAGE_B(0, 1, 0);
    WAITV(0);
    BARRIER();
#pragma unroll
    for (int m = 0; m < 4; ++m) { aF[0][m] = RD_A(0, 0, m); aF[1][m] = RD_A(0, 1, m); }
#pragma unroll
    for (int nn = 0; nn < 2; ++nn) { bFa[0][nn] = RD_B(0, 0, nn); bFa[1][nn] = RD_B(0, 1, nn); }
    LGKM0();                       // preload fully in regs before any wave
    BARRIER();                     // can overwrite tile0 regions (A0(2)@P1)
    STAGE_A(1, 0, BK); STAGE_A(1, 1, BK);

#pragma unroll 1
    for (int i = 0; i < 15; ++i) {         // tiles 0..29
        const int t2 = 2 * i;
        TILE(0, (t2 + 2) * BK, (t2 + 1) * BK);
        TILE(1, (t2 + 3) * BK, (t2 + 2) * BK);
    }

    // ---- tile 30 (buf0): stage only B(31); drain fully at W2 ----
    STAGE_B(1, 0, 31 * BK); STAGE_B(1, 1, 31 * BK);
    MMA_BW(0, bFa, bFb, 0, 1);
    MMA_BW(1, bFb, bFa, 0, 2);
    WAITV(2); BARRIER();
    MMA_BW(2, bFa, bFb, 0, 3);
    MMA_P4(bFb, bFa, 1);
    WAITV(0); BARRIER();
    // ---- tile 31 (buf1): no stages, no barriers needed ----
    MMA_BW(0, bFa, bFb, 1, 1);
    MMA_BW(1, bFb, bFa, 1, 2);
    MMA_BW(2, bFa, bFb, 1, 3);
    MMA_END(bFb);

    // ---- C write: C/D layout col = lane&15, row = (lane>>4)*4 + reg ----
#pragma unroll
    for (int m = 0; m < 4; ++m) {
        const int rbase = m0 + wm * 64 + m * 16 + q * 4;
        const float4 s4 = *(const float4*)&sx[rbase];
#pragma unroll
        for (int n = 0; n < 8; ++n) {
            const int col = n0 + wn * 128 + n * 16 + r4;
            const float swc = sw[col];
            float* cp = C + (size_t)rbase * N_DIM + col;
            cp[0 * N_DIM] = (float)acc[m][n][0] * s4.x * swc;
            cp[1 * N_DIM] = (float)acc[m][n][1] * s4.y * swc;
            cp[2 * N_DIM] = (float)acc[m][n][2] * s4.z * swc;
            cp[3 * N_DIM] = (float)acc[m][n][3] * s4.w * swc;
        }
    }
#undef STAGE_A
#undef STAGE_B
#undef RD_A
#undef RD_B
#undef MMA_BW
#undef MMA_P4
#undef MMA_END
#undef TILE
}

// ---------------------------------------------------------------------------
// Launch: ws usage = 16.7 MB xq + 16.7 MB wq + 32 KB scales.
// ---------------------------------------------------------------------------
extern "C" void kernel_launch(void* const* d_in, const int* in_sizes, int n_in,
                              void* d_out, int out_size, void* d_ws, size_t ws_size,
                              hipStream_t stream) {
    const float* x      = (const float*)d_in[0];
    const int*   packed = (const int*)d_in[1];
    const float* d      = (const float*)d_in[2];
    const float* dmin   = (const float*)d_in[3];
    const int*   scales = (const int*)d_in[4];
    const int*   mins   = (const int*)d_in[5];
    float* out = (float*)d_out;

    int8_t* xq = (int8_t*)d_ws;                               // 16.7 MB
    int8_t* wq = xq + (size_t)M_DIM * K_DIM;                  // 16.7 MB
    float*  sx = (float*)(wq + (size_t)N_DIM * K_DIM);        // 16 KB
    float*  sw = sx + M_DIM;                                  // 16 KB

    quant_xw<<<8192, 256, 0, stream>>>(x, packed, d, dmin, scales, mins,
                                       xq, sx, wq, sw);
    gemm_i8<<<256, 512, 0, stream>>>(xq, wq, sx, sw, out);
}